// Round 7
// baseline (718.468 us; speedup 1.0000x reference)
//
#include <hip/hip_runtime.h>
#include <math.h>
#include <stdint.h>

#define ND_ROWS 16384
#define DDIM    256
#define KCODES  8192
#define NSEG    128        // 64-code segments
#define NRG     8          // row groups (XCD-affine), 2048 rows each

typedef _Float16 f16x4 __attribute__((ext_vector_type(4)));
typedef _Float16 f16x8 __attribute__((ext_vector_type(8)));
typedef float    f32x4 __attribute__((ext_vector_type(4)));

// ---------------------------------------------------------------------------
// ws layout (bytes):
//   minpair [0,        131072)   u64[16384]  (memset 0xFF each call)
//   counts  [131072,   163840)   int[8192]   (memset 0 each call)
//   parts   [163840,   196608)   de[4096] | dq[4096]
//   ne      [196608,   229376)   float[8192]
//   Ap      [229376,   17006592) 16384 x 512 f16  ([x_hi(256) | x_lo(256)])
//   Bp      [17006592, 25395200) 8192  x 512 f16  ([e_hi | e_lo])
// total ~25.4 MB
// ---------------------------------------------------------------------------

__device__ __attribute__((always_inline)) inline void load_lds16(const void* g, void* l) {
    __builtin_amdgcn_global_load_lds((const __attribute__((address_space(1))) void*)g,
                                     (__attribute__((address_space(3))) void*)l, 16, 0, 0);
}

// one wave per vector: fp16 hi/lo split; squared-norm only for codebook rows
__global__ __launch_bounds__(256) void prep_kernel(const float* __restrict__ x,
                                                   const float* __restrict__ emb,
                                                   _Float16* __restrict__ Ap,
                                                   _Float16* __restrict__ Bp,
                                                   float* __restrict__ ne) {
    int wave = (blockIdx.x << 2) + (threadIdx.x >> 6);   // [0, 24576)
    int lane = threadIdx.x & 63;
    const float* src;
    _Float16* dst;
    if (wave < ND_ROWS) { src = x + (size_t)wave * DDIM; dst = Ap + (size_t)wave * 512; }
    else { int r = wave - ND_ROWS; src = emb + (size_t)r * DDIM; dst = Bp + (size_t)r * 512; }
    float4 v = ((const float4*)src)[lane];
    f16x4 hi, lo;
    hi[0] = (_Float16)v.x; lo[0] = (_Float16)(v.x - (float)hi[0]);
    hi[1] = (_Float16)v.y; lo[1] = (_Float16)(v.y - (float)hi[1]);
    hi[2] = (_Float16)v.z; lo[2] = (_Float16)(v.z - (float)hi[2]);
    hi[3] = (_Float16)v.w; lo[3] = (_Float16)(v.w - (float)hi[3]);
    *(f16x4*)(dst + lane * 4)       = hi;
    *(f16x4*)(dst + 256 + lane * 4) = lo;
    if (wave >= ND_ROWS) {
        float s = v.x*v.x + v.y*v.y + v.z*v.z + v.w*v.w;
        #pragma unroll
        for (int m = 32; m; m >>= 1) s += __shfl_xor(s, m, 64);
        if (lane == 0) ne[wave - ND_ROWS] = s;
    }
}

// Persistent-B-segment argmin. Block = (rgroup = blockIdx&7 [XCD-affine rows],
// seg = blockIdx>>3 [64 codes]). B slab (64 codes x full K, hi+lo = 64 KB) is
// loaded to LDS ONCE; A rows stream through registers from L2 (each XCD's
// blocks share one 2 MB A slice). K-loop has NO barriers. argmin uses
// dist' = ne - 2*dot (row-constant ||x||^2 dropped - argmin-invariant).
// Cross-segment merge: packed u64 atomicMin (flip(dist)<<32 | idx).
// LDS chunk swizzle: phys slot = chunk ^ (code&7) (0 conflicts in R4-R6).
__global__ __launch_bounds__(256, 2) void argmin_seg(
    const _Float16* __restrict__ Ap, const _Float16* __restrict__ Bp,
    const float* __restrict__ ne, unsigned long long* __restrict__ minpair) {
    __shared__ __align__(16) _Float16 Bs[64 * 512];   // 64 KB

    const int tid  = threadIdx.x;
    const int lane = tid & 63;
    const int w    = tid >> 6;
    const int quad = lane >> 4;
    const int t16  = lane & 15;

    const int rgroup  = blockIdx.x & 7;
    const int seg     = blockIdx.x >> 3;
    const int rowBase = rgroup * 2048;
    const int code0   = seg * 64;

    // stage B slab: wave w stages local codes [w*16, w*16+16), one 1 KB row per
    // instr; lane l -> phys slot l holding logical chunk l ^ (code&7).
    #pragma unroll
    for (int i = 0; i < 16; ++i) {
        int cl = w * 16 + i;
        int g  = lane ^ (cl & 7);
        const char* gB = (const char*)(Bp + (size_t)(code0 + cl) * 512) + g * 16;
        load_lds16(gB, (char*)Bs + cl * 1024);
    }
    float nec[4];
    #pragma unroll
    for (int nt = 0; nt < 4; ++nt) nec[nt] = ne[code0 + nt * 16 + t16];
    __syncthreads();   // the only barrier

    // wave w owns rows [rowBase + w*512, +512) in 8 chunks of 64
    for (int chunk = 0; chunk < 8; ++chunk) {
        const int m0 = rowBase + w * 512 + chunk * 64;
        f32x4 acc[4][4];
        #pragma unroll
        for (int mt = 0; mt < 4; ++mt)
            #pragma unroll
            for (int nt = 0; nt < 4; ++nt) {
                f32x4 z = {0.0f, 0.0f, 0.0f, 0.0f};
                acc[mt][nt] = z;
            }

        #pragma unroll
        for (int kc = 0; kc < 8; ++kc) {
            f16x8 ah[4], al[4], bh[4], bl[4];
            #pragma unroll
            for (int mt = 0; mt < 4; ++mt) {
                const char* ga = (const char*)(Ap + (size_t)(m0 + mt * 16 + t16) * 512);
                ah[mt] = *(const f16x8*)(ga + (kc * 4 + quad) * 16);
                al[mt] = *(const f16x8*)(ga + 512 + (kc * 4 + quad) * 16);
            }
            #pragma unroll
            for (int nt = 0; nt < 4; ++nt) {
                int cl = nt * 16 + t16;
                int ph = (kc * 4 + quad) ^ (cl & 7);
                int pl = (32 + kc * 4 + quad) ^ (cl & 7);
                bh[nt] = *(const f16x8*)((const char*)Bs + cl * 1024 + ph * 16);
                bl[nt] = *(const f16x8*)((const char*)Bs + cl * 1024 + pl * 16);
            }
            #pragma unroll
            for (int mt = 0; mt < 4; ++mt)
                #pragma unroll
                for (int nt = 0; nt < 4; ++nt)
                    acc[mt][nt] = __builtin_amdgcn_mfma_f32_16x16x32_f16(ah[mt], bh[nt], acc[mt][nt], 0, 0, 0);
            #pragma unroll
            for (int mt = 0; mt < 4; ++mt)
                #pragma unroll
                for (int nt = 0; nt < 4; ++nt)
                    acc[mt][nt] = __builtin_amdgcn_mfma_f32_16x16x32_f16(ah[mt], bl[nt], acc[mt][nt], 0, 0, 0);
            #pragma unroll
            for (int mt = 0; mt < 4; ++mt)
                #pragma unroll
                for (int nt = 0; nt < 4; ++nt)
                    acc[mt][nt] = __builtin_amdgcn_mfma_f32_16x16x32_f16(al[mt], bh[nt], acc[mt][nt], 0, 0, 0);
        }

        // epilogue: per (mt,reg) row, argmin over this segment's 64 codes,
        // then one packed atomicMin per row. nt ascending + strict < => first-wins.
        #pragma unroll
        for (int mt = 0; mt < 4; ++mt)
            #pragma unroll
            for (int r = 0; r < 4; ++r) {
                float best = nec[0] - 2.0f * acc[mt][0][r];
                int   bi   = code0 + t16;
                #pragma unroll
                for (int nt = 1; nt < 4; ++nt) {
                    float d = nec[nt] - 2.0f * acc[mt][nt][r];
                    if (d < best) { best = d; bi = code0 + nt * 16 + t16; }
                }
                #pragma unroll
                for (int m = 1; m < 16; m <<= 1) {
                    float ov = __shfl_xor(best, m, 64);
                    int   oi = __shfl_xor(bi, m, 64);
                    if (ov < best || (ov == best && oi < bi)) { best = ov; bi = oi; }
                }
                if (t16 == 0) {
                    int row = m0 + mt * 16 + quad * 4 + r;
                    unsigned u = __float_as_uint(best);
                    u = (u & 0x80000000u) ? ~u : (u | 0x80000000u);   // total-order map
                    unsigned long long packed = ((unsigned long long)u << 32) | (unsigned)bi;
                    atomicMin(&minpair[row], packed);
                }
            }
    }
}

// decode packed min, gather codebook row, write quantized_sg + float index,
// histogram atomic + per-block SSE partials.
__global__ __launch_bounds__(256) void finalize_kernel(
    const float* __restrict__ x, const float* __restrict__ emb,
    const unsigned long long* __restrict__ minpair,
    float* __restrict__ out_q, float* __restrict__ out_idx,
    int* __restrict__ counts, float* __restrict__ parts) {
    __shared__ float rde[4], rdq[4];
    int wv   = threadIdx.x >> 6;
    int row  = (blockIdx.x << 2) + wv;
    int lane = threadIdx.x & 63;

    int bi = (int)(minpair[row] & 0xFFFFFFFFull);

    float4 xv = ((const float4*)(x   + (size_t)row * DDIM))[lane];
    float4 ev = ((const float4*)(emb + (size_t)bi  * DDIM))[lane];
    float4 q;
    q.x = xv.x + (ev.x - xv.x);
    q.y = xv.y + (ev.y - xv.y);
    q.z = xv.z + (ev.z - xv.z);
    q.w = xv.w + (ev.w - xv.w);
    ((float4*)(out_q + (size_t)row * DDIM))[lane] = q;

    float de = (ev.x - xv.x) * (ev.x - xv.x) + (ev.y - xv.y) * (ev.y - xv.y)
             + (ev.z - xv.z) * (ev.z - xv.z) + (ev.w - xv.w) * (ev.w - xv.w);
    float dq = (q.x - ev.x) * (q.x - ev.x) + (q.y - ev.y) * (q.y - ev.y)
             + (q.z - ev.z) * (q.z - ev.z) + (q.w - ev.w) * (q.w - ev.w);
    #pragma unroll
    for (int m = 32; m; m >>= 1) {
        de += __shfl_xor(de, m, 64);
        dq += __shfl_xor(dq, m, 64);
    }
    if (lane == 0) {
        out_idx[row] = (float)bi;
        atomicAdd(&counts[bi], 1);
        rde[wv] = de; rdq[wv] = dq;
    }
    __syncthreads();
    if (threadIdx.x == 0) {
        parts[blockIdx.x]        = rde[0] + rde[1] + rde[2] + rde[3];
        parts[4096 + blockIdx.x] = rdq[0] + rdq[1] + rdq[2] + rdq[3];
    }
}

__global__ __launch_bounds__(256) void scalars_kernel(
    const int* __restrict__ counts, const float* __restrict__ parts,
    float* __restrict__ out_loss, float* __restrict__ out_perp) {
    __shared__ float red[256], rde[256], rdq[256];
    float local = 0.0f, de = 0.0f, dq = 0.0f;
    for (int k = threadIdx.x; k < KCODES; k += 256) {
        float p = (float)counts[k] * (1.0f / (float)ND_ROWS);
        local += p * logf(p + 1e-10f);
    }
    for (int k = threadIdx.x; k < 4096; k += 256) {
        de += parts[k];
        dq += parts[4096 + k];
    }
    red[threadIdx.x] = local; rde[threadIdx.x] = de; rdq[threadIdx.x] = dq;
    __syncthreads();
    for (int s = 128; s; s >>= 1) {
        if (threadIdx.x < s) {
            red[threadIdx.x] += red[threadIdx.x + s];
            rde[threadIdx.x] += rde[threadIdx.x + s];
            rdq[threadIdx.x] += rdq[threadIdx.x + s];
        }
        __syncthreads();
    }
    if (threadIdx.x == 0) {
        *out_perp = expf(-red[0]);
        float invn = 1.0f / (float)(ND_ROWS * DDIM);
        *out_loss = rdq[0] * invn + 0.25f * (rde[0] * invn);
    }
}

extern "C" void kernel_launch(void* const* d_in, const int* in_sizes, int n_in,
                              void* d_out, int out_size, void* d_ws, size_t ws_size,
                              hipStream_t stream) {
    const float* x   = (const float*)d_in[0];
    const float* emb = (const float*)d_in[1];

    char* ws = (char*)d_ws;
    unsigned long long* minpair = (unsigned long long*)ws;         // 128 KB
    int*      counts = (int*)(ws + 131072);                        // 32 KB
    float*    parts  = (float*)(ws + 163840);                      // 32 KB
    float*    ne     = (float*)(ws + 196608);                      // 32 KB
    _Float16* Ap     = (_Float16*)(ws + 229376);                   // 16.8 MB
    _Float16* Bp     = (_Float16*)(ws + 17006592);                 // 8.4 MB

    float* out_q    = (float*)d_out;
    float* out_idx  = out_q + (size_t)ND_ROWS * DDIM;
    float* out_loss = out_idx + ND_ROWS;
    float* out_perp = out_loss + 1;

    hipMemsetAsync(minpair, 0xFF, ND_ROWS * sizeof(unsigned long long), stream);
    hipMemsetAsync(counts, 0, KCODES * sizeof(int), stream);

    prep_kernel<<<(KCODES + ND_ROWS) / 4, 256, 0, stream>>>(x, emb, Ap, Bp, ne);
    argmin_seg<<<NRG * NSEG, 256, 0, stream>>>(Ap, Bp, ne, minpair);
    finalize_kernel<<<ND_ROWS / 4, 256, 0, stream>>>(x, emb, minpair,
                                                     out_q, out_idx, counts, parts);
    scalars_kernel<<<1, 256, 0, stream>>>(counts, parts, out_loss, out_perp);
}

// Round 8
// 423.555 us; speedup vs baseline: 1.6963x; 1.6963x over previous
//
#include <hip/hip_runtime.h>
#include <math.h>
#include <stdint.h>

#define ND_ROWS 16384
#define DDIM    256
#define KCODES  8192
#define NSPLIT  8
#define KSEG    (KCODES / NSPLIT)   // 1024

typedef _Float16 f16x4 __attribute__((ext_vector_type(4)));
typedef _Float16 f16x8 __attribute__((ext_vector_type(8)));
typedef float    f32x4 __attribute__((ext_vector_type(4)));

// ---------------------------------------------------------------------------
// ws layout (bytes):
//   minpair [0,        131072)   u64[16384]  (memset 0xFF each call)
//   counts  [131072,   163840)   int[8192]   (memset 0 each call)
//   parts   [163840,   196608)   de[4096] | dq[4096]
//   ne      [196608,   229376)   float[8192]
//   Ap      [229376,   17006592) 16384 x 512 f16  ([x_hi(256) | x_lo(256)])
//   Bp      [17006592, 25395200) 8192  x 512 f16  ([e_hi | e_lo])
// ---------------------------------------------------------------------------

__device__ __attribute__((always_inline)) inline void load_lds16(const void* g, void* l) {
    __builtin_amdgcn_global_load_lds((const __attribute__((address_space(1))) void*)g,
                                     (__attribute__((address_space(3))) void*)l, 16, 0, 0);
}

// one wave per vector: fp16 hi/lo split; squared-norm only for codebook rows
__global__ __launch_bounds__(256) void prep_kernel(const float* __restrict__ x,
                                                   const float* __restrict__ emb,
                                                   _Float16* __restrict__ Ap,
                                                   _Float16* __restrict__ Bp,
                                                   float* __restrict__ ne) {
    int wave = (blockIdx.x << 2) + (threadIdx.x >> 6);   // [0, 24576)
    int lane = threadIdx.x & 63;
    const float* src;
    _Float16* dst;
    if (wave < ND_ROWS) { src = x + (size_t)wave * DDIM; dst = Ap + (size_t)wave * 512; }
    else { int r = wave - ND_ROWS; src = emb + (size_t)r * DDIM; dst = Bp + (size_t)r * 512; }
    float4 v = ((const float4*)src)[lane];
    f16x4 hi, lo;
    hi[0] = (_Float16)v.x; lo[0] = (_Float16)(v.x - (float)hi[0]);
    hi[1] = (_Float16)v.y; lo[1] = (_Float16)(v.y - (float)hi[1]);
    hi[2] = (_Float16)v.z; lo[2] = (_Float16)(v.z - (float)hi[2]);
    hi[3] = (_Float16)v.w; lo[3] = (_Float16)(v.w - (float)hi[3]);
    *(f16x4*)(dst + lane * 4)       = hi;
    *(f16x4*)(dst + 256 + lane * 4) = lo;
    if (wave >= ND_ROWS) {
        float s = v.x*v.x + v.y*v.y + v.z*v.z + v.w*v.w;
        #pragma unroll
        for (int m = 32; m; m >>= 1) s += __shfl_xor(s, m, 64);
        if (lane == 0) ne[wave - ND_ROWS] = s;
    }
}

// MFMA argmin GEMM, dot = x1.e1 + x1.e2 + x2.e1 (fp16 hi/lo split).
// Block tile 128 rows x 256 cols (R6 traffic shape: A issue 512 MB, B
// XCD-resident via ks=blockIdx&7), but EIGHT waves of 64x64 so per-wave
// regs = acc 64 AGPR + ~64 VGPR = 128 -> 4 waves/SIMD (R6's acc[4][8] cost
// 256/wave -> only 2). 2 blocks/CU, grid 1024 = two even rounds.
// dist' = ne - 2*dot (row-constant ||x||^2 dropped, argmin-invariant).
// Cross-block merge: packed u64 atomicMin (flip(dist)<<32 | idx, first-wins).
// LDS slot swizzle (0 conflicts measured R4-R6): phys slot = chunk ^ (row&7).
__global__ __launch_bounds__(512, 4) void argmin_mfma(
    const _Float16* __restrict__ Ap, const _Float16* __restrict__ Bp,
    const float* __restrict__ ne, unsigned long long* __restrict__ minpair) {
    __shared__ __align__(16) _Float16 As[128 * 64];   // [row][hi32|lo32] = 128 B, 16 KB
    __shared__ __align__(16) _Float16 Bs[256 * 64];   // 32 KB

    const int tid  = threadIdx.x;
    const int lane = tid & 63;
    const int w    = tid >> 6;   // 0..7
    const int wx   = w & 3;      // 64-col quarter
    const int wy   = w >> 2;     // 64-row half
    const int quad = lane >> 4;
    const int t16  = lane & 15;

    const int ks       = blockIdx.x & 7;    // XCD-affine code split
    const int rt       = blockIdx.x >> 3;   // 128 row tiles
    const int rowBase  = rt * 128;
    const int codeBase = ks * KSEG;

    // staging: lane l -> row-offset l/8, phys slot l&7 holding logical chunk
    // g = (l&7) ^ ((l>>3)&7); goff selects 16B piece + hi/lo half.
    const int l8   = lane >> 3;
    const int g    = (lane & 7) ^ (l8 & 7);
    const int goff = ((g & 3) << 3) + ((g >> 2) << 8);   // f16 units

    float minval[16];
    int   minidx[16];
    #pragma unroll
    for (int i = 0; i < 16; ++i) { minval[i] = 3.402823466e+38f; minidx[i] = 0; }

    const int sA = quad ^ (t16 & 7);         // hi-frag phys slot
    const int sL = (quad ^ 4) ^ (t16 & 7);   // lo-frag phys slot

    for (int jt = 0; jt < KSEG / 256; ++jt) {
        const int colBase = codeBase + jt * 256;
        f32x4 acc[4][4];
        #pragma unroll
        for (int mt = 0; mt < 4; ++mt)
            #pragma unroll
            for (int nt = 0; nt < 4; ++nt) {
                f32x4 z = {0.0f, 0.0f, 0.0f, 0.0f};
                acc[mt][nt] = z;
            }

        for (int kc = 0; kc < 256; kc += 32) {
            __syncthreads();
            #pragma unroll
            for (int j = 0; j < 2; ++j) {   // A: 128 rows, 16 per wave
                int rr = w * 16 + j * 8 + l8;
                const char* gA = (const char*)(Ap + (size_t)(rowBase + rr) * 512 + kc + goff);
                load_lds16(gA, (char*)As + ((w * 2 + j) << 10));
            }
            #pragma unroll
            for (int j = 0; j < 4; ++j) {   // B: 256 rows, 32 per wave
                int rr = w * 32 + j * 8 + l8;
                const char* gB = (const char*)(Bp + (size_t)(colBase + rr) * 512 + kc + goff);
                load_lds16(gB, (char*)Bs + ((w * 4 + j) << 10));
            }
            __syncthreads();

            f16x8 ah[4];
            #pragma unroll
            for (int mt = 0; mt < 4; ++mt) {
                int r = wy * 64 + mt * 16 + t16;
                ah[mt] = *(const f16x8*)((const char*)As + r * 128 + (sA << 4));
            }
            {   // hh
                f16x8 bh[4];
                #pragma unroll
                for (int nt = 0; nt < 4; ++nt) {
                    int r = wx * 64 + nt * 16 + t16;
                    bh[nt] = *(const f16x8*)((const char*)Bs + r * 128 + (sA << 4));
                }
                #pragma unroll
                for (int mt = 0; mt < 4; ++mt)
                    #pragma unroll
                    for (int nt = 0; nt < 4; ++nt)
                        acc[mt][nt] = __builtin_amdgcn_mfma_f32_16x16x32_f16(ah[mt], bh[nt], acc[mt][nt], 0, 0, 0);
            }
            {   // hl
                f16x8 bl[4];
                #pragma unroll
                for (int nt = 0; nt < 4; ++nt) {
                    int r = wx * 64 + nt * 16 + t16;
                    bl[nt] = *(const f16x8*)((const char*)Bs + r * 128 + (sL << 4));
                }
                #pragma unroll
                for (int mt = 0; mt < 4; ++mt)
                    #pragma unroll
                    for (int nt = 0; nt < 4; ++nt)
                        acc[mt][nt] = __builtin_amdgcn_mfma_f32_16x16x32_f16(ah[mt], bl[nt], acc[mt][nt], 0, 0, 0);
            }
            {   // lh: fresh al, re-read bh
                f16x8 al[4], bh2[4];
                #pragma unroll
                for (int mt = 0; mt < 4; ++mt) {
                    int r = wy * 64 + mt * 16 + t16;
                    al[mt] = *(const f16x8*)((const char*)As + r * 128 + (sL << 4));
                }
                #pragma unroll
                for (int nt = 0; nt < 4; ++nt) {
                    int r = wx * 64 + nt * 16 + t16;
                    bh2[nt] = *(const f16x8*)((const char*)Bs + r * 128 + (sA << 4));
                }
                #pragma unroll
                for (int mt = 0; mt < 4; ++mt)
                    #pragma unroll
                    for (int nt = 0; nt < 4; ++nt)
                        acc[mt][nt] = __builtin_amdgcn_mfma_f32_16x16x32_f16(al[mt], bh2[nt], acc[mt][nt], 0, 0, 0);
            }
        }

        // epilogue: dist' = ne - 2*dot; nt ascending + strict < => first-wins
        #pragma unroll
        for (int nt = 0; nt < 4; ++nt) {
            int col = colBase + wx * 64 + nt * 16 + t16;
            float nec = ne[col];
            #pragma unroll
            for (int mt = 0; mt < 4; ++mt)
                #pragma unroll
                for (int r = 0; r < 4; ++r) {
                    float d = nec - 2.0f * acc[mt][nt][r];
                    if (d < minval[mt * 4 + r]) { minval[mt * 4 + r] = d; minidx[mt * 4 + r] = col; }
                }
        }
    }

    // reduce over t16 (lane bits 0-3; stays within quad), tie -> smaller index,
    // then one packed atomicMin per row from each t16==0 lane.
    #pragma unroll
    for (int i = 0; i < 16; ++i) {
        float v = minval[i]; int ix = minidx[i];
        #pragma unroll
        for (int m = 1; m < 16; m <<= 1) {
            float ov = __shfl_xor(v, m, 64);
            int   oi = __shfl_xor(ix, m, 64);
            if (ov < v || (ov == v && oi < ix)) { v = ov; ix = oi; }
        }
        if (t16 == 0) {
            int mt = i >> 2, r = i & 3;
            int row = rowBase + wy * 64 + mt * 16 + quad * 4 + r;
            unsigned u = __float_as_uint(v);
            u = (u & 0x80000000u) ? ~u : (u | 0x80000000u);   // total-order map
            unsigned long long packed = ((unsigned long long)u << 32) | (unsigned)ix;
            atomicMin(&minpair[row], packed);
        }
    }
}

// decode packed min, gather codebook row, write quantized_sg + float index,
// histogram atomic + per-block SSE partials.
__global__ __launch_bounds__(256) void finalize_kernel(
    const float* __restrict__ x, const float* __restrict__ emb,
    const unsigned long long* __restrict__ minpair,
    float* __restrict__ out_q, float* __restrict__ out_idx,
    int* __restrict__ counts, float* __restrict__ parts) {
    __shared__ float rde[4], rdq[4];
    int wv   = threadIdx.x >> 6;
    int row  = (blockIdx.x << 2) + wv;
    int lane = threadIdx.x & 63;

    int bi = (int)(minpair[row] & 0xFFFFFFFFull);

    float4 xv = ((const float4*)(x   + (size_t)row * DDIM))[lane];
    float4 ev = ((const float4*)(emb + (size_t)bi  * DDIM))[lane];
    float4 q;
    q.x = xv.x + (ev.x - xv.x);
    q.y = xv.y + (ev.y - xv.y);
    q.z = xv.z + (ev.z - xv.z);
    q.w = xv.w + (ev.w - xv.w);
    ((float4*)(out_q + (size_t)row * DDIM))[lane] = q;

    float de = (ev.x - xv.x) * (ev.x - xv.x) + (ev.y - xv.y) * (ev.y - xv.y)
             + (ev.z - xv.z) * (ev.z - xv.z) + (ev.w - xv.w) * (ev.w - xv.w);
    float dq = (q.x - ev.x) * (q.x - ev.x) + (q.y - ev.y) * (q.y - ev.y)
             + (q.z - ev.z) * (q.z - ev.z) + (q.w - ev.w) * (q.w - ev.w);
    #pragma unroll
    for (int m = 32; m; m >>= 1) {
        de += __shfl_xor(de, m, 64);
        dq += __shfl_xor(dq, m, 64);
    }
    if (lane == 0) {
        out_idx[row] = (float)bi;
        atomicAdd(&counts[bi], 1);
        rde[wv] = de; rdq[wv] = dq;
    }
    __syncthreads();
    if (threadIdx.x == 0) {
        parts[blockIdx.x]        = rde[0] + rde[1] + rde[2] + rde[3];
        parts[4096 + blockIdx.x] = rdq[0] + rdq[1] + rdq[2] + rdq[3];
    }
}

__global__ __launch_bounds__(256) void scalars_kernel(
    const int* __restrict__ counts, const float* __restrict__ parts,
    float* __restrict__ out_loss, float* __restrict__ out_perp) {
    __shared__ float red[256], rde[256], rdq[256];
    float local = 0.0f, de = 0.0f, dq = 0.0f;
    for (int k = threadIdx.x; k < KCODES; k += 256) {
        float p = (float)counts[k] * (1.0f / (float)ND_ROWS);
        local += p * logf(p + 1e-10f);
    }
    for (int k = threadIdx.x; k < 4096; k += 256) {
        de += parts[k];
        dq += parts[4096 + k];
    }
    red[threadIdx.x] = local; rde[threadIdx.x] = de; rdq[threadIdx.x] = dq;
    __syncthreads();
    for (int s = 128; s; s >>= 1) {
        if (threadIdx.x < s) {
            red[threadIdx.x] += red[threadIdx.x + s];
            rde[threadIdx.x] += rde[threadIdx.x + s];
            rdq[threadIdx.x] += rdq[threadIdx.x + s];
        }
        __syncthreads();
    }
    if (threadIdx.x == 0) {
        *out_perp = expf(-red[0]);
        float invn = 1.0f / (float)(ND_ROWS * DDIM);
        *out_loss = rdq[0] * invn + 0.25f * (rde[0] * invn);
    }
}

extern "C" void kernel_launch(void* const* d_in, const int* in_sizes, int n_in,
                              void* d_out, int out_size, void* d_ws, size_t ws_size,
                              hipStream_t stream) {
    const float* x   = (const float*)d_in[0];
    const float* emb = (const float*)d_in[1];

    char* ws = (char*)d_ws;
    unsigned long long* minpair = (unsigned long long*)ws;         // 128 KB
    int*      counts = (int*)(ws + 131072);                        // 32 KB
    float*    parts  = (float*)(ws + 163840);                      // 32 KB
    float*    ne     = (float*)(ws + 196608);                      // 32 KB
    _Float16* Ap     = (_Float16*)(ws + 229376);                   // 16.8 MB
    _Float16* Bp     = (_Float16*)(ws + 17006592);                 // 8.4 MB

    float* out_q    = (float*)d_out;
    float* out_idx  = out_q + (size_t)ND_ROWS * DDIM;
    float* out_loss = out_idx + ND_ROWS;
    float* out_perp = out_loss + 1;

    hipMemsetAsync(minpair, 0xFF, ND_ROWS * sizeof(unsigned long long), stream);
    hipMemsetAsync(counts, 0, KCODES * sizeof(int), stream);

    prep_kernel<<<(KCODES + ND_ROWS) / 4, 256, 0, stream>>>(x, emb, Ap, Bp, ne);
    argmin_mfma<<<(ND_ROWS / 128) * NSPLIT, 512, 0, stream>>>(Ap, Bp, ne, minpair);
    finalize_kernel<<<ND_ROWS / 4, 256, 0, stream>>>(x, emb, minpair,
                                                     out_q, out_idx, counts, parts);
    scalars_kernel<<<1, 256, 0, stream>>>(counts, parts, out_loss, out_perp);
}